// Round 7
// baseline (358.554 us; speedup 1.0000x reference)
//
#include <hip/hip_runtime.h>

#define NT 256

// v8 = v5 structure (32KB LDS, XOR swizzle, scalar math, high occupancy) with
// two units (4 rows) per block processed sequentially:
//  - hoisted across units: sincos (t/m2-only), swizzle bases, H[k] coeffs
//    (per-thread k is unit-invariant), bias.
//  - unit1's 32 global loads issue during unit0's back half (register
//    prefetch) -> per-block cold-start HBM wait paid once, not twice.
//  - unit0's stores drain under unit1's compute.
// v6/v7 lesson: latency-hiding capacity ~ occupancy x independent streams;
// 64KB/2-block configs lose. Keep 32KB and the v5 stream structure.
// launch_bounds(NT,4): 128-VGPR budget; est. peak ~124. FETCH_SIZE = spill tripwire.

template<bool INV>
__device__ __forceinline__ void dft16(float* vr, float* vi) {
    constexpr float C1 = 0.9238795325112867f;   // cos(pi/8)
    constexpr float S1 = 0.3826834323650898f;   // sin(pi/8)
    constexpr float HF = 0.7071067811865476f;
    const float WR[10] = {1.f,  C1,  HF,  S1, 0.f, 0.f, -HF, 0.f, 0.f, -C1};
    const float WI[10] = {0.f, -S1, -HF, -C1, -1.f, 0.f, -HF, 0.f, 0.f,  S1};

    float ar[16], ai[16];
    #pragma unroll
    for (int jl = 0; jl < 4; ++jl) {
        float x0r = vr[jl],      x0i = vi[jl];
        float x1r = vr[jl + 4],  x1i = vi[jl + 4];
        float x2r = vr[jl + 8],  x2i = vi[jl + 8];
        float x3r = vr[jl + 12], x3i = vi[jl + 12];
        float t0r = x0r + x2r, t0i = x0i + x2i;
        float t1r = x0r - x2r, t1i = x0i - x2i;
        float t2r = x1r + x3r, t2i = x1i + x3i;
        float t3r = x1r - x3r, t3i = x1i - x3i;
        ar[jl]     = t0r + t2r;  ai[jl]     = t0i + t2i;
        ar[jl + 8] = t0r - t2r;  ai[jl + 8] = t0i - t2i;
        if (!INV) {
            ar[jl + 4]  = t1r + t3i;  ai[jl + 4]  = t1i - t3r;  // t1 - i*t3
            ar[jl + 12] = t1r - t3i;  ai[jl + 12] = t1i + t3r;  // t1 + i*t3
        } else {
            ar[jl + 4]  = t1r - t3i;  ai[jl + 4]  = t1i + t3r;
            ar[jl + 12] = t1r + t3i;  ai[jl + 12] = t1i - t3r;
        }
    }
    #pragma unroll
    for (int k4 = 1; k4 < 4; ++k4) {
        #pragma unroll
        for (int jl = 1; jl < 4; ++jl) {
            const int e = jl * k4;
            float wr = WR[e];
            float wi = INV ? -WI[e] : WI[e];
            const int id = jl + 4 * k4;
            float xr = ar[id], xi = ai[id];
            ar[id] = xr * wr - xi * wi;
            ai[id] = xr * wi + xi * wr;
        }
    }
    #pragma unroll
    for (int k4 = 0; k4 < 4; ++k4) {
        float x0r = ar[4*k4 + 0], x0i = ai[4*k4 + 0];
        float x1r = ar[4*k4 + 1], x1i = ai[4*k4 + 1];
        float x2r = ar[4*k4 + 2], x2i = ai[4*k4 + 2];
        float x3r = ar[4*k4 + 3], x3i = ai[4*k4 + 3];
        float t0r = x0r + x2r, t0i = x0i + x2i;
        float t1r = x0r - x2r, t1i = x0i - x2i;
        float t2r = x1r + x3r, t2i = x1i + x3i;
        float t3r = x1r - x3r, t3i = x1i - x3i;
        vr[k4]     = t0r + t2r;  vi[k4]     = t0i + t2i;
        vr[k4 + 8] = t0r - t2r;  vi[k4 + 8] = t0i - t2i;
        if (!INV) {
            vr[k4 + 4]  = t1r + t3i;  vi[k4 + 4]  = t1i - t3r;
            vr[k4 + 12] = t1r - t3i;  vi[k4 + 12] = t1i + t3r;
        } else {
            vr[k4 + 4]  = t1r - t3i;  vi[k4 + 4]  = t1i + t3r;
            vr[k4 + 12] = t1r + t3i;  vi[k4 + 12] = t1i - t3r;
        }
    }
}

// v[e] *= (wr,wi)^e for e=1..15; two chains stepping by w^2.
__device__ __forceinline__ void apply_tw_powers(float* vr, float* vi, float wr, float wi) {
    const float w2r = wr * wr - wi * wi;
    const float w2i = 2.0f * wr * wi;
    float aor = wr,  aoi = wi;
    float aer = w2r, aei = w2i;
    #pragma unroll
    for (int e = 1; e < 16; e += 2) {
        { float xr = vr[e], xi = vi[e];
          vr[e] = xr * aor - xi * aoi;
          vi[e] = xr * aoi + xi * aor; }
        if (e + 1 < 16) {
            float xr = vr[e + 1], xi = vi[e + 1];
            vr[e + 1] = xr * aer - xi * aei;
            vi[e + 1] = xr * aei + xi * aer;
        }
        if (e + 2 < 16) {
            float nr = aor * w2r - aoi * w2i, ni = aor * w2i + aoi * w2r;
            aor = nr; aoi = ni;
            nr = aer * w2r - aei * w2i; ni = aer * w2i + aei * w2r;
            aer = nr; aei = ni;
        }
    }
}

// One 2-row unit: full fwd FFT -> pointwise -> inverse -> store.
// If PRE: issue next unit's 32 global loads after exchange-2 read (covers
// stage C + pointwise + entire inverse, ~tens of us >> HBM latency).
template<bool PRE>
__device__ __forceinline__ void process_unit(
    float2* lds, const int t, const int ax, const int m2,
    const int (&swzbase)[8], const int c2,
    const float cA, const float sA, const float cB, const float sB,
    const float (&hR)[8], const float (&hI)[8], const float bv,
    float (&vr)[16], float (&vi)[16],
    float (&pr)[16], float (&pi)[16],
    const float* __restrict__ xnext,
    float* __restrict__ oa)
{
    // ---- stage A: DFT16 over j -> digit a; twiddle W4096^{t*a} ----
    dft16<false>(vr, vi);
    apply_tw_powers(vr, vi, cA, sA);

    // ---- exchange 1 write: l = 256a + t; phys = 256a + tswz (b64) ----
    {
        const int tswz = t ^ ((t >> 3) & 0xE);
        #pragma unroll
        for (int a = 0; a < 16; ++a)
            lds[(a << 8) + tswz] = make_float2(vr[a], vi[a]);
    }
    __syncthreads();

    // ---- exchange 1 read: l = 256ax + 16q + m2 (b64) ----
    #pragma unroll
    for (int q = 0; q < 16; ++q) {
        float2 v = lds[swzbase[q & 7] + (q << 4)];
        vr[q] = v.x; vi[q] = v.y;
    }

    // ---- stage B ----
    dft16<false>(vr, vi);
    apply_tw_powers(vr, vi, cB, sB);

    // ---- exchange 2 write: wave-local (16-lane groups) ----
    #pragma unroll
    for (int b = 0; b < 16; ++b)
        lds[swzbase[b & 7] + (b << 4)] = make_float2(vr[b], vi[b]);
    __builtin_amdgcn_wave_barrier();

    // ---- exchange 2 read: b128 at l0 = 256ax + 16*m2, phys offset m^c2 ----
    const float2* __restrict__ pbase = &lds[(ax << 8) + (m2 << 4)];
    #pragma unroll
    for (int m = 0; m < 16; m += 2) {
        float4 v = *(const float4*)&pbase[m ^ c2];
        vr[m] = v.x;     vi[m] = v.y;
        vr[m + 1] = v.z; vi[m + 1] = v.w;
    }

    // ---- prefetch next unit (covers the rest of this unit's pipeline) ----
    if constexpr (PRE) {
        #pragma unroll
        for (int j = 0; j < 16; ++j) {
            pr[j] = xnext[(j << 8) + t];
            pi[j] = xnext[(j << 8) + t + 4096];
        }
    }

    // ---- stage C ----
    dft16<false>(vr, vi);

    // ---- pointwise H[k]/N (hoisted coefficients) ----
    {
        #pragma unroll
        for (int r3 = 0; r3 < 4; ++r3) {
            float xr = vr[r3], xi = vi[r3];
            vr[r3] = xr * hR[r3] - xi * hI[r3];
            vi[r3] = xr * hI[r3] + xi * hR[r3];
        }
        #pragma unroll
        for (int r3 = 4; r3 < 12; ++r3) { vr[r3] = 0.0f; vi[r3] = 0.0f; }
        {
            float xr = vr[12], xi = vi[12];
            vr[12] = xr * hR[4] - xi * hI[4];
            vi[12] = xr * hI[4] + xi * hR[4];
        }
        #pragma unroll
        for (int r3 = 13; r3 < 16; ++r3) {
            float xr = vr[r3], xi = vi[r3];
            vr[r3] = xr * hR[r3 - 8] - xi * hI[r3 - 8];
            vi[r3] = xr * hI[r3 - 8] + xi * hR[r3 - 8];
        }
    }

    // ---- inverse: exact adjoint ----
    dft16<true>(vr, vi);

    {
        float2* __restrict__ pw = &lds[(ax << 8) + (m2 << 4)];
        #pragma unroll
        for (int m = 0; m < 16; m += 2)
            *(float4*)&pw[m ^ c2] = make_float4(vr[m], vi[m], vr[m + 1], vi[m + 1]);
    }
    __builtin_amdgcn_wave_barrier();

    #pragma unroll
    for (int b = 0; b < 16; ++b) {
        float2 v = lds[swzbase[b & 7] + (b << 4)];
        vr[b] = v.x; vi[b] = v.y;
    }

    apply_tw_powers(vr, vi, cB, -sB);
    dft16<true>(vr, vi);

    #pragma unroll
    for (int q = 0; q < 16; ++q)
        lds[swzbase[q & 7] + (q << 4)] = make_float2(vr[q], vi[q]);
    __syncthreads();

    {
        const int tswz = t ^ ((t >> 3) & 0xE);
        #pragma unroll
        for (int a = 0; a < 16; ++a) {
            float2 v = lds[(a << 8) + tswz];
            vr[a] = v.x; vi[a] = v.y;
        }
    }

    apply_tw_powers(vr, vi, cA, -sA);
    dft16<true>(vr, vi);

    #pragma unroll
    for (int j = 0; j < 16; ++j) {
        __builtin_nontemporal_store(vr[j] + bv, &oa[(j << 8) + t]);
        __builtin_nontemporal_store(vi[j] + bv, &oa[(j << 8) + t + 4096]);
    }
}

__global__ __launch_bounds__(NT, 4) void spectral_circulant_r16v8(
    const float* __restrict__ x,
    const float* __restrict__ w_real,
    const float* __restrict__ w_imag,
    const float* __restrict__ bias_p,
    float* __restrict__ out)
{
    __shared__ __align__(16) float2 lds[4096];   // 32 KB

    const int t   = threadIdx.x;
    const int blk = blockIdx.x;                  // 2048 blocks; units blk, blk+2048
    const int ax  = t >> 4;
    const int m2  = t & 15;

    // ---- hoisted per-thread state (unit-invariant) ----
    int swzbase[8];
    #pragma unroll
    for (int c = 0; c < 8; ++c)
        swzbase[c] = (ax << 8) + (m2 ^ (c << 1));
    const int c2 = (m2 & 7) << 1;

    float sA, cA, sB, cB;
    __sincosf((float)t  * -1.5339807878856412e-3f, &sA, &cA);  // -2pi/4096
    __sincosf((float)m2 * -2.454369260617026e-2f, &sB, &cB);   // -2pi/256

    float hR[8], hI[8];
    {
        const int c = (m2 << 4) | ax;            // k lower byte, in [0,255]
        const float sc = 1.0f / 4096.0f;
        #pragma unroll
        for (int r3 = 0; r3 < 4; ++r3) {         // k = 256*r3 + c < 1024
            hR[r3] = w_real[(r3 << 8) + c] * sc;
            hI[r3] = w_imag[(r3 << 8) + c] * sc;
        }
        {                                        // r3=12: k=3072+c, active iff c>0
            const int idx = 1024 - c;
            const float mm = (c > 0) ? sc : 0.0f;
            hR[4] = w_real[idx] * mm;
            hI[4] = -w_imag[idx] * mm;
        }
        #pragma unroll
        for (int r3 = 13; r3 < 16; ++r3) {       // conj mirror
            const int idx = ((16 - r3) << 8) - c;
            hR[r3 - 8] = w_real[idx] * sc;
            hI[r3 - 8] = -w_imag[idx] * sc;
        }
    }
    const float bv = bias_p[0];

    // ---- unit 0 load ----
    float vrA[16], viA[16], vrB[16], viB[16];
    const float* __restrict__ xa0 = x + (size_t)(2 * blk) * 4096;
    const float* __restrict__ xa1 = x + (size_t)(2 * (blk + 2048)) * 4096;
    float* __restrict__ oa0 = out + (size_t)(2 * blk) * 4096;
    float* __restrict__ oa1 = out + (size_t)(2 * (blk + 2048)) * 4096;

    #pragma unroll
    for (int j = 0; j < 16; ++j) {
        vrA[j] = xa0[(j << 8) + t];
        viA[j] = xa0[(j << 8) + t + 4096];
    }

    // ---- unit 0 (prefetches unit 1 into vrB/viB) ----
    process_unit<true>(lds, t, ax, m2, swzbase, c2, cA, sA, cB, sB,
                       hR, hI, bv, vrA, viA, vrB, viB, xa1, oa0);

    __syncthreads();   // LDS WAR guard between units

    // ---- unit 1 ----
    process_unit<false>(lds, t, ax, m2, swzbase, c2, cA, sA, cB, sB,
                        hR, hI, bv, vrB, viB, vrA, viA, nullptr, oa1);
}

extern "C" void kernel_launch(void* const* d_in, const int* in_sizes, int n_in,
                              void* d_out, int out_size, void* d_ws, size_t ws_size,
                              hipStream_t stream) {
    (void)in_sizes; (void)n_in; (void)d_ws; (void)ws_size; (void)out_size;
    const float* x      = (const float*)d_in[0];   // (8192, 4096) f32
    const float* w_real = (const float*)d_in[1];   // (2049,) f32
    const float* w_imag = (const float*)d_in[2];   // (2049,) f32
    const float* bias   = (const float*)d_in[3];   // scalar f32
    float* out = (float*)d_out;                    // (8192, 4096) f32

    spectral_circulant_r16v8<<<2048, NT, 0, stream>>>(x, w_real, w_imag, bias, out);
}

// Round 8
// 243.523 us; speedup vs baseline: 1.4724x; 1.4724x over previous
//
#include <hip/hip_runtime.h>

#define NT 256

// v9 = v5 structure (32 KB LDS, XOR swizzle, 2 rows/block, occ ~35%) with
// complex values packed as v2f {re,im} -> butterflies become v_pk_add/sub_f32,
// complex muls become pk_mul+pk_fma. Unlike v7's (P,Q) packing this changes
// NOTHING structural: LDS float2 slot == the v2f, same 32 KB, same exchanges,
// same register footprint (complex value was 2 VGPRs before and after).
// v8 lesson: peak live regs must stay well under the launch_bounds cap;
// this kernel's peak ~= v5's (~70) << 128.
// FETCH/WRITE_SIZE = spill tripwire (must stay ~65.7e3 / ~131e3 KB).

typedef float v2f __attribute__((ext_vector_type(2)));
typedef float v4f __attribute__((ext_vector_type(4)));

// z * (wr + i*wi) = wr*z + wi*{-z.y, z.x}  -> pk_mul + pk_fma (+shuffle)
__device__ __forceinline__ v2f cmulc(v2f z, float wr, float wi) {
    v2f t; t.x = -z.y; t.y = z.x;
    return wr * z + wi * t;
}

// 16-point DFT on packed complex: v[k] = sum_j v[j] * w16^{jk}
// (INV=true: conjugated; unnormalized). Natural order in/out.
template<bool INV>
__device__ __forceinline__ void dft16(v2f* v) {
    constexpr float C1 = 0.9238795325112867f;   // cos(pi/8)
    constexpr float S1 = 0.3826834323650898f;   // sin(pi/8)
    constexpr float HF = 0.7071067811865476f;
    const float WR[10] = {1.f,  C1,  HF,  S1, 0.f, 0.f, -HF, 0.f, 0.f, -C1};
    const float WI[10] = {0.f, -S1, -HF, -C1, -1.f, 0.f, -HF, 0.f, 0.f,  S1};

    v2f a[16];
    #pragma unroll
    for (int jl = 0; jl < 4; ++jl) {
        v2f x0 = v[jl], x1 = v[jl + 4], x2 = v[jl + 8], x3 = v[jl + 12];
        v2f t0 = x0 + x2, t1 = x0 - x2;
        v2f t2 = x1 + x3, t3 = x1 - x3;
        a[jl]     = t0 + t2;
        a[jl + 8] = t0 - t2;
        v2f it3; it3.x = -t3.y; it3.y = t3.x;    // i*t3
        if (!INV) {
            a[jl + 4]  = t1 - it3;               // t1 - i*t3
            a[jl + 12] = t1 + it3;
        } else {
            a[jl + 4]  = t1 + it3;
            a[jl + 12] = t1 - it3;
        }
    }
    #pragma unroll
    for (int k4 = 1; k4 < 4; ++k4) {
        #pragma unroll
        for (int jl = 1; jl < 4; ++jl) {
            const int e = jl * k4;
            const int id = jl + 4 * k4;
            a[id] = cmulc(a[id], WR[e], INV ? -WI[e] : WI[e]);
        }
    }
    #pragma unroll
    for (int k4 = 0; k4 < 4; ++k4) {
        v2f x0 = a[4*k4 + 0], x1 = a[4*k4 + 1], x2 = a[4*k4 + 2], x3 = a[4*k4 + 3];
        v2f t0 = x0 + x2, t1 = x0 - x2;
        v2f t2 = x1 + x3, t3 = x1 - x3;
        v[k4]     = t0 + t2;
        v[k4 + 8] = t0 - t2;
        v2f it3; it3.x = -t3.y; it3.y = t3.x;
        if (!INV) {
            v[k4 + 4]  = t1 - it3;
            v[k4 + 12] = t1 + it3;
        } else {
            v[k4 + 4]  = t1 + it3;
            v[k4 + 12] = t1 - it3;
        }
    }
}

// v[e] *= (wr,wi)^e for e=1..15; two scalar power chains stepping by w^2
// (halves serial chain latency), packed application.
__device__ __forceinline__ void apply_tw(v2f* v, float wr, float wi) {
    const float w2r = wr * wr - wi * wi;
    const float w2i = 2.0f * wr * wi;
    float aor = wr,  aoi = wi;    // odd powers
    float aer = w2r, aei = w2i;   // even powers
    #pragma unroll
    for (int e = 1; e < 16; e += 2) {
        v[e] = cmulc(v[e], aor, aoi);
        if (e + 1 < 16)
            v[e + 1] = cmulc(v[e + 1], aer, aei);
        if (e + 2 < 16) {
            float nr = aor * w2r - aoi * w2i, ni = aor * w2i + aoi * w2r;
            aor = nr; aoi = ni;
            nr = aer * w2r - aei * w2i; ni = aer * w2i + aei * w2r;
            aer = nr; aei = ni;
        }
    }
}

__global__ __launch_bounds__(NT, 4) void spectral_circulant_r16v9(
    const float* __restrict__ x,
    const float* __restrict__ w_real,
    const float* __restrict__ w_imag,
    const float* __restrict__ bias_p,
    float* __restrict__ out)
{
    __shared__ __align__(16) v2f lds[4096];   // 32 KB, same as v5

    const int t   = threadIdx.x;
    const int blk = blockIdx.x;

    v2f v[16];

    // ---- load two rows: z = rowA + i*rowB; reg j holds x[256j + t] ----
    const float* __restrict__ xa = x + (size_t)(2 * blk) * 4096;
    const float* __restrict__ xb = xa + 4096;
    #pragma unroll
    for (int j = 0; j < 16; ++j) {
        v2f z; z.x = xa[(j << 8) + t]; z.y = xb[(j << 8) + t];
        v[j] = z;
    }

    // ---- stage A: DFT16 over j -> digit a; twiddle W4096^{t*a} ----
    dft16<false>(v);
    float sA, cA;
    __sincosf((float)t * -1.5339807878856412e-3f, &sA, &cA);  // -2pi/4096
    apply_tw(v, cA, sA);

    // ---- exchange 1 write: l = 256a + t; phys = 256a + tswz (b64) ----
    {
        const int tswz = t ^ ((t >> 3) & 0xE);   // t ^ (((t>>4)&7)<<1)
        #pragma unroll
        for (int a = 0; a < 16; ++a)
            lds[(a << 8) + tswz] = v[a];
    }
    __syncthreads();

    const int ax = t >> 4;               // upper digit this thread owns from here on
    const int m2 = t & 15;               // lower digit

    // 8 swizzled column bases: phys(256ax + 16q + m2) = swzbase[q&7] + 16q.
    int swzbase[8];
    #pragma unroll
    for (int c = 0; c < 8; ++c)
        swzbase[c] = (ax << 8) + (m2 ^ (c << 1));

    // ---- exchange 1 read: l = 256ax + 16q + m2 (b64) ----
    #pragma unroll
    for (int q = 0; q < 16; ++q)
        v[q] = lds[swzbase[q & 7] + (q << 4)];

    // ---- stage B: DFT16 over q -> digit b; twiddle W256^{m2*b} ----
    dft16<false>(v);
    float sB, cB;
    __sincosf((float)m2 * -2.454369260617026e-2f, &sB, &cB);  // -2pi/256
    apply_tw(v, cB, sB);

    // ---- exchange 2 write: l = 256ax + 16b + m2 — wave-local (16-lane groups),
    // per-wave in-order DS pipe + wave_barrier suffice, no block barrier ----
    #pragma unroll
    for (int b = 0; b < 16; ++b)
        lds[swzbase[b & 7] + (b << 4)] = v[b];
    __builtin_amdgcn_wave_barrier();

    // ---- exchange 2 read: 16 contiguous at l0 = 256ax + 16*m2;
    // phys = l0 + (m ^ c2), c2 even -> slot pairs adjacent+16B-aligned (b128) ----
    const int c2 = (m2 & 7) << 1;
    const int l0 = (ax << 8) + (m2 << 4);
    #pragma unroll
    for (int m = 0; m < 16; m += 2) {
        v4f r4 = *(const v4f*)&lds[l0 + (m ^ c2)];
        v[m]     = r4.xy;
        v[m + 1] = r4.zw;
    }

    // ---- stage C: DFT16 over m -> digit r3; freq k = 256*r3 + 16*m2 + ax ----
    dft16<false>(v);

    // ---- pointwise H[k]/N ----
    {
        const int c = (m2 << 4) | ax;            // in [0,255]
        const float sc = 1.0f / 4096.0f;
        #pragma unroll
        for (int r3 = 0; r3 < 4; ++r3) {         // k < 1024: active
            const int k = (r3 << 8) + c;
            v[r3] = cmulc(v[r3], w_real[k] * sc, w_imag[k] * sc);
        }
        #pragma unroll
        for (int r3 = 4; r3 < 12; ++r3)          // truncated band
            v[r3] = (v2f){0.0f, 0.0f};
        {                                        // r3=12: k=3072+c, active iff c>0
            const int idx = 1024 - c;
            const float mm = (c > 0) ? sc : 0.0f;
            v[12] = cmulc(v[12], w_real[idx] * mm, -w_imag[idx] * mm);
        }
        #pragma unroll
        for (int r3 = 13; r3 < 16; ++r3) {       // k > 3072: conj mirror
            const int idx = ((16 - r3) << 8) - c;
            v[r3] = cmulc(v[r3], w_real[idx] * sc, -w_imag[idx] * sc);
        }
    }

    // ================= inverse: exact adjoint, reverse order =================

    // ---- C^H ----
    dft16<true>(v);

    // ---- exchange 2 reverse write (b128) ----
    #pragma unroll
    for (int m = 0; m < 16; m += 2) {
        v4f r4; r4.xy = v[m]; r4.zw = v[m + 1];
        *(v4f*)&lds[l0 + (m ^ c2)] = r4;
    }
    __builtin_amdgcn_wave_barrier();

    // ---- exchange 2 reverse read: l = 256ax + 16b + m2 over b (b64) ----
    #pragma unroll
    for (int b = 0; b < 16; ++b)
        v[b] = lds[swzbase[b & 7] + (b << 4)];

    // ---- B^H ----
    apply_tw(v, cB, -sB);
    dft16<true>(v);

    // ---- exchange 1 reverse write ----
    #pragma unroll
    for (int q = 0; q < 16; ++q)
        lds[swzbase[q & 7] + (q << 4)] = v[q];
    __syncthreads();

    // ---- exchange 1 reverse read: l = 256a + t ----
    {
        const int tswz = t ^ ((t >> 3) & 0xE);
        #pragma unroll
        for (int a = 0; a < 16; ++a)
            v[a] = lds[(a << 8) + tswz];
    }

    // ---- A^H ----
    apply_tw(v, cA, -sA);
    dft16<true>(v);

    // ---- store (nontemporal: streamed output) ----
    const float bv = bias_p[0];
    float* __restrict__ oa = out + (size_t)(2 * blk) * 4096;
    float* __restrict__ ob = oa + 4096;
    #pragma unroll
    for (int j = 0; j < 16; ++j) {
        __builtin_nontemporal_store(v[j].x + bv, &oa[(j << 8) + t]);
        __builtin_nontemporal_store(v[j].y + bv, &ob[(j << 8) + t]);
    }
}

extern "C" void kernel_launch(void* const* d_in, const int* in_sizes, int n_in,
                              void* d_out, int out_size, void* d_ws, size_t ws_size,
                              hipStream_t stream) {
    (void)in_sizes; (void)n_in; (void)d_ws; (void)ws_size; (void)out_size;
    const float* x      = (const float*)d_in[0];   // (8192, 4096) f32
    const float* w_real = (const float*)d_in[1];   // (2049,) f32
    const float* w_imag = (const float*)d_in[2];   // (2049,) f32
    const float* bias   = (const float*)d_in[3];   // scalar f32
    float* out = (float*)d_out;                    // (8192, 4096) f32

    spectral_circulant_r16v9<<<8192 / 2, NT, 0, stream>>>(x, w_real, w_imag, bias, out);
}